// Round 4
// baseline (382.279 us; speedup 1.0000x reference)
//
#include <hip/hip_runtime.h>

#define NN 100000
#define EE 1600000
#define FO 32
#define NBKT 512
#define DPB 196            // dst nodes per bucket; NBKT*DPB = 100352 >= NN
#define RND 6144           // edges per multisplit block (LDS staging 48KB)

// ---------------- threefry2x32 with key (0,1) = jax.random.key(1) -------
__device__ __forceinline__ unsigned rotl32(unsigned x, unsigned r) {
    return (x << r) | (x >> (32u - r));
}

__device__ __forceinline__ void threefry2x32_01(unsigned x0, unsigned x1,
                                                unsigned& y0, unsigned& y1) {
    const unsigned ks0 = 0u, ks1 = 1u, ks2 = 0x1BD11BDBu;
    x0 += ks0; x1 += ks1;
#define TF_R(r) { x0 += x1; x1 = rotl32(x1, (r)); x1 ^= x0; }
    TF_R(13) TF_R(15) TF_R(26) TF_R(6)   x0 += ks1; x1 += ks2 + 1u;
    TF_R(17) TF_R(29) TF_R(16) TF_R(24)  x0 += ks2; x1 += ks0 + 2u;
    TF_R(13) TF_R(15) TF_R(26) TF_R(6)   x0 += ks0; x1 += ks1 + 3u;
    TF_R(17) TF_R(29) TF_R(16) TF_R(24)  x0 += ks1; x1 += ks2 + 4u;
    TF_R(13) TF_R(15) TF_R(26) TF_R(6)   x0 += ks2; x1 += ks0 + 5u;
#undef TF_R
    y0 = x0; y1 = x1;
}

__device__ __forceinline__ unsigned short f2bf(float f) {   // RNE
    unsigned u = __float_as_uint(f);
    unsigned r = (u + 0x7fffu + ((u >> 16) & 1u)) >> 16;
    return (unsigned short)r;
}
__device__ __forceinline__ float bf2f(unsigned short b) {
    return __uint_as_float(((unsigned)b) << 16);
}

// ---------------- K0: detect edge_index storage width -------------------
__global__ __launch_bounds__(256) void k_detect(const unsigned* __restrict__ ei,
                                                unsigned* __restrict__ flag) {
    __shared__ unsigned red[256];
    unsigned v = 0;
    for (int i = threadIdx.x; i < 4096; i += 256) v |= ei[2 * i + 1];
    red[threadIdx.x] = v;
    __syncthreads();
    for (int s = 128; s; s >>= 1) {
        if (threadIdx.x < s) red[threadIdx.x] |= red[threadIdx.x + s];
        __syncthreads();
    }
    if (threadIdx.x == 0) *flag = (red[0] == 0u) ? 1u : 0u;  // 1 => int64
}

__device__ __forceinline__ int load_idx(const int* __restrict__ ei,
                                        int logical, unsigned wide) {
    return ei[wide ? (logical << 1) : logical];
}

// ---------------- K1: h(bf16) = x @ W, fused a_src/a_dst ----------------
__global__ __launch_bounds__(256) void k_gemm(
    const float* __restrict__ x, const float* __restrict__ W,
    const float* __restrict__ att_s, const float* __restrict__ att_d,
    unsigned short* __restrict__ h16,
    float* __restrict__ a_s, float* __restrict__ a_d)
{
    __shared__ float Ws[256 * 32];
    __shared__ float xs[32 * 132];
    const int tid = threadIdx.x;

    #pragma unroll
    for (int i = 0; i < 8; ++i) {
        int idx = i * 1024 + tid * 4;
        *reinterpret_cast<float4*>(Ws + idx) =
            *reinterpret_cast<const float4*>(W + idx);
    }

    const int j4 = tid & 7;
    const int rl = tid >> 3;
    const int c0 = j4 * 4;
    const float4 avs = *reinterpret_cast<const float4*>(att_s + c0);
    const float4 avd = *reinterpret_cast<const float4*>(att_d + c0);

    for (int tile = blockIdx.x; tile < (NN / 32); tile += gridDim.x) {
        const int row0 = tile * 32;
        float4 acc = make_float4(0.f, 0.f, 0.f, 0.f);

        for (int kc = 0; kc < 256; kc += 128) {
            __syncthreads();
            #pragma unroll
            for (int i = 0; i < 4; ++i) {
                int l = i * 1024 + tid * 4;
                int r = l >> 7, c = l & 127;
                *reinterpret_cast<float4*>(xs + r * 132 + c) =
                    *reinterpret_cast<const float4*>(
                        x + (size_t)(row0 + r) * 256 + kc + c);
            }
            __syncthreads();
            const float* xr = xs + rl * 132;
            #pragma unroll 4
            for (int k0 = 0; k0 < 128; k0 += 4) {
                float4 xv = *reinterpret_cast<const float4*>(xr + k0);
                #pragma unroll
                for (int q = 0; q < 4; ++q) {
                    float xq = (q == 0) ? xv.x : (q == 1) ? xv.y
                             : (q == 2) ? xv.z : xv.w;
                    float4 wv = *reinterpret_cast<const float4*>(
                        Ws + (kc + k0 + q) * 32 + c0);
                    acc.x = fmaf(xq, wv.x, acc.x);
                    acc.y = fmaf(xq, wv.y, acc.y);
                    acc.z = fmaf(xq, wv.z, acc.z);
                    acc.w = fmaf(xq, wv.w, acc.w);
                }
            }
        }
        const int row = row0 + rl;
        ushort4 hb;
        hb.x = f2bf(acc.x); hb.y = f2bf(acc.y);
        hb.z = f2bf(acc.z); hb.w = f2bf(acc.w);
        *reinterpret_cast<ushort4*>(h16 + (size_t)row * 32 + c0) = hb;
        float v1 = acc.x * avs.x + acc.y * avs.y + acc.z * avs.z + acc.w * avs.w;
        float v2 = acc.x * avd.x + acc.y * avd.y + acc.z * avd.z + acc.w * avd.w;
        #pragma unroll
        for (int off = 4; off; off >>= 1) {
            v1 += __shfl_xor(v1, off, 8);
            v2 += __shfl_xor(v2, off, 8);
        }
        if (j4 == 0) { a_s[row] = v1; a_d[row] = v2; }
    }
}

// ---------------- K_A: global bucket histogram --------------------------
__global__ __launch_bounds__(256) void k_hist(
    const int* __restrict__ ei, const unsigned* __restrict__ flag,
    int* __restrict__ bhist)
{
    __shared__ int hl[NBKT];
    const int tid = threadIdx.x;
    for (int i = tid; i < NBKT; i += 256) hl[i] = 0;
    __syncthreads();
    const unsigned wide = *flag;
    const int base = blockIdx.x * 8192;
    #pragma unroll
    for (int k = 0; k < 32; ++k) {
        int e = base + k * 256 + tid;
        if (e < EE) {
            unsigned d = (unsigned)load_idx(ei, EE + e, wide);
            atomicAdd(&hl[d / DPB], 1);
        }
    }
    __syncthreads();
    for (int i = tid; i < NBKT; i += 256)
        if (hl[i]) atomicAdd(&bhist[i], hl[i]);
}

// ---------------- K_B: scan 512 bucket counts -> offs, gcursor ----------
__global__ __launch_bounds__(256) void k_scan(
    const int* __restrict__ bhist, int* __restrict__ offs,
    int* __restrict__ gcursor)
{
    __shared__ int pair[256];
    const int t = threadIdx.x;
    int a0 = bhist[2 * t], a1 = bhist[2 * t + 1];
    pair[t] = a0 + a1;
    __syncthreads();
    for (int off = 1; off < 256; off <<= 1) {
        int add = (t >= off) ? pair[t - off] : 0;
        __syncthreads();
        pair[t] += add;
        __syncthreads();
    }
    int excl = pair[t] - a0 - a1;
    offs[2 * t] = excl;           gcursor[2 * t] = excl;
    offs[2 * t + 1] = excl + a0;  gcursor[2 * t + 1] = excl + a0;
    if (t == 255) offs[NBKT] = pair[255];
}

// ---------------- K_C: multisplit scatter (coalesced writes) ------------
__global__ __launch_bounds__(256) void k_msplit(
    const int* __restrict__ ei, const unsigned* __restrict__ flag,
    int* __restrict__ gcursor, int2* __restrict__ packed)
{
    __shared__ int2 staged[RND];       // 48 KB
    __shared__ int hist[NBKT], base[NBKT], rcnt[NBKT], gposL[NBKT];
    __shared__ int pair[256];
    const int tid = threadIdx.x;
    const int chunk0 = blockIdx.x * RND;
    const unsigned wide = *flag;

    for (int i = tid; i < NBKT; i += 256) { hist[i] = 0; rcnt[i] = 0; }
    __syncthreads();
    #pragma unroll
    for (int k = 0; k < RND / 256; ++k) {
        int e = chunk0 + k * 256 + tid;
        if (e < EE) {
            unsigned d = (unsigned)load_idx(ei, EE + e, wide);
            atomicAdd(&hist[d / DPB], 1);
        }
    }
    __syncthreads();
    // block scan of hist -> base (pair trick: 256 threads, 512 entries)
    int h0 = hist[2 * tid], h1 = hist[2 * tid + 1];
    pair[tid] = h0 + h1;
    __syncthreads();
    for (int off = 1; off < 256; off <<= 1) {
        int add = (tid >= off) ? pair[tid - off] : 0;
        __syncthreads();
        pair[tid] += add;
        __syncthreads();
    }
    int excl = pair[tid] - h0 - h1;
    base[2 * tid] = excl;
    base[2 * tid + 1] = excl + h0;
    // reserve global space (one atomic per non-empty bucket)
    for (int b = tid; b < NBKT; b += 256) {
        int c = hist[b];
        if (c) gposL[b] = atomicAdd(&gcursor[b], c);
    }
    __syncthreads();
    // place edges into LDS at bucket-sorted positions
    #pragma unroll
    for (int k = 0; k < RND / 256; ++k) {
        int e = chunk0 + k * 256 + tid;
        if (e < EE) {
            int s = load_idx(ei, e, wide);
            int d = load_idx(ei, EE + e, wide);
            int b = (unsigned)d / DPB;
            int lp = base[b] + atomicAdd(&rcnt[b], 1);
            staged[lp] = make_int2(s, d);
        }
    }
    __syncthreads();
    // stream out: consecutive i within a bucket -> consecutive global pos
    int nv = EE - chunk0; if (nv > RND) nv = RND;
    for (int i = tid; i < nv; i += 256) {
        int2 ed = staged[i];
        int b = (unsigned)ed.y / DPB;
        packed[gposL[b] + (i - base[b])] = ed;
    }
}

// ---------------- K_D: bucket aggregate + full fused epilogue -----------
__global__ __launch_bounds__(256) void k_aggr(
    const int2* __restrict__ packed, const int* __restrict__ offs,
    const unsigned short* __restrict__ h16,
    const float* __restrict__ a_s, const float* __restrict__ a_d,
    const float* __restrict__ bias, float* __restrict__ out)
{
    __shared__ float accL[DPB * 33];   // stride 33: banks spread by node id
    __shared__ float denL[DPB];
    __shared__ float wselfL[DPB];
    const int tid = threadIdx.x;
    const int b = blockIdx.x;
    const int d0 = b * DPB;
    int cnt = NN - d0; if (cnt > DPB) cnt = DPB;
    if (cnt <= 0) return;

    for (int i = tid; i < DPB * 33; i += 256) accL[i] = 0.f;
    for (int i = tid; i < DPB; i += 256) denL[i] = 0.f;
    __syncthreads();

    const int e0 = offs[b], e1 = offs[b + 1];
    for (int i = e0 + tid; i < e1; i += 256) {
        int2 ed = packed[i];
        const int s = ed.x, dd = ed.y;
        float al = a_s[s] + a_d[dd];
        al = (al >= 0.f) ? al : 0.2f * al;
        float w = __expf(al);
        const int nl = dd - d0;
        atomicAdd(&denL[nl], w);
        const uint4* hp = reinterpret_cast<const uint4*>(h16 + (size_t)s * 32);
        uint4 r0 = hp[0], r1 = hp[1], r2 = hp[2], r3 = hp[3];
        float* arow = accL + nl * 33;
#define DO(u, q) \
        atomicAdd(arow + 2*(q),     w * __uint_as_float((u) << 16)); \
        atomicAdd(arow + 2*(q) + 1, w * __uint_as_float((u) & 0xffff0000u));
        DO(r0.x, 0) DO(r0.y, 1) DO(r0.z, 2) DO(r0.w, 3)
        DO(r1.x, 4) DO(r1.y, 5) DO(r1.z, 6) DO(r1.w, 7)
        DO(r2.x, 8) DO(r2.y, 9) DO(r2.z, 10) DO(r2.w, 11)
        DO(r3.x, 12) DO(r3.y, 13) DO(r3.z, 14) DO(r3.w, 15)
#undef DO
    }
    __syncthreads();
    // self-loop weights (one thread per node, no atomics needed)
    for (int n = tid; n < cnt; n += 256) {
        int d = d0 + n;
        float al = a_s[d] + a_d[d];
        al = (al >= 0.f) ? al : 0.2f * al;
        float w = __expf(al);
        wselfL[n] = w;
        denL[n] += w;
    }
    __syncthreads();
    // finalize: /denom + bias + relu + threefry dropout, coalesced store
    for (int idx = tid; idx < cnt * 32; idx += 256) {
        int n = idx >> 5, c = idx & 31;
        int d = d0 + n;
        float hv = bf2f(h16[(size_t)d * 32 + c]);
        float v = (accL[n * 33 + c] + wselfL[n] * hv) / denL[n];
        v = fmaxf(v + bias[c], 0.f);
        int t = d * 32 + c;
        unsigned y0, y1;
        threefry2x32_01(0u, (unsigned)t, y0, y1);
        out[t] = ((y0 ^ y1) >> 31) ? 0.f : v * 2.f;
    }
}

extern "C" void kernel_launch(void* const* d_in, const int* in_sizes, int n_in,
                              void* d_out, int out_size, void* d_ws, size_t ws_size,
                              hipStream_t stream) {
    const float* x     = (const float*)d_in[0];
    const float* W     = (const float*)d_in[1];
    const float* att_s = (const float*)d_in[2];
    const float* att_d = (const float*)d_in[3];
    const float* bias  = (const float*)d_in[4];
    const int*   ei    = (const int*)d_in[5];
    float* out = (float*)d_out;

    // ws layout: packed[EE] int2 | h16[NN*32] bf16 | a_s | a_d | bhist[512]
    //            | offs[513] | gcursor[512] | flag
    int2* packed = (int2*)d_ws;
    unsigned short* h16 = (unsigned short*)(packed + EE);
    float* a_s = (float*)(h16 + (size_t)NN * FO);
    float* a_d = a_s + NN;
    int* bhist = (int*)(a_d + NN);
    int* offs = bhist + NBKT;
    int* gcursor = offs + (NBKT + 1);
    unsigned* flag = (unsigned*)(gcursor + NBKT);

    hipMemsetAsync(bhist, 0, NBKT * sizeof(int), stream);

    k_detect<<<1, 256, 0, stream>>>((const unsigned*)ei, flag);
    k_gemm<<<1024, 256, 0, stream>>>(x, W, att_s, att_d, h16, a_s, a_d);
    k_hist<<<(EE + 8191) / 8192, 256, 0, stream>>>(ei, flag, bhist);
    k_scan<<<1, 256, 0, stream>>>(bhist, offs, gcursor);
    k_msplit<<<(EE + RND - 1) / RND, 256, 0, stream>>>(ei, flag, gcursor, packed);
    k_aggr<<<(NN + DPB - 1) / DPB, 256, 0, stream>>>(packed, offs, h16, a_s, a_d, bias, out);
}

// Round 5
// 381.431 us; speedup vs baseline: 1.0022x; 1.0022x over previous
//
#include <hip/hip_runtime.h>

#define NN 100000
#define EE 1600000
#define FO 32
#define NBKT 512
#define DPB 196            // dst nodes per bucket; NBKT*DPB = 100352 >= NN
#define RND 6144           // edges per multisplit block (LDS staging 48KB)

// ---------------- threefry2x32 with key (0,1) = jax.random.key(1) -------
__device__ __forceinline__ unsigned rotl32(unsigned x, unsigned r) {
    return (x << r) | (x >> (32u - r));
}

__device__ __forceinline__ void threefry2x32_01(unsigned x0, unsigned x1,
                                                unsigned& y0, unsigned& y1) {
    const unsigned ks0 = 0u, ks1 = 1u, ks2 = 0x1BD11BDBu;
    x0 += ks0; x1 += ks1;
#define TF_R(r) { x0 += x1; x1 = rotl32(x1, (r)); x1 ^= x0; }
    TF_R(13) TF_R(15) TF_R(26) TF_R(6)   x0 += ks1; x1 += ks2 + 1u;
    TF_R(17) TF_R(29) TF_R(16) TF_R(24)  x0 += ks2; x1 += ks0 + 2u;
    TF_R(13) TF_R(15) TF_R(26) TF_R(6)   x0 += ks0; x1 += ks1 + 3u;
    TF_R(17) TF_R(29) TF_R(16) TF_R(24)  x0 += ks1; x1 += ks2 + 4u;
    TF_R(13) TF_R(15) TF_R(26) TF_R(6)   x0 += ks2; x1 += ks0 + 5u;
#undef TF_R
    y0 = x0; y1 = x1;
}

__device__ __forceinline__ unsigned short f2bf(float f) {   // RNE
    unsigned u = __float_as_uint(f);
    unsigned r = (u + 0x7fffu + ((u >> 16) & 1u)) >> 16;
    return (unsigned short)r;
}
__device__ __forceinline__ float bf2f(unsigned short b) {
    return __uint_as_float(((unsigned)b) << 16);
}

// ---------------- K0: detect edge_index storage width -------------------
__global__ __launch_bounds__(256) void k_detect(const unsigned* __restrict__ ei,
                                                unsigned* __restrict__ flag) {
    __shared__ unsigned red[256];
    unsigned v = 0;
    for (int i = threadIdx.x; i < 4096; i += 256) v |= ei[2 * i + 1];
    red[threadIdx.x] = v;
    __syncthreads();
    for (int s = 128; s; s >>= 1) {
        if (threadIdx.x < s) red[threadIdx.x] |= red[threadIdx.x + s];
        __syncthreads();
    }
    if (threadIdx.x == 0) *flag = (red[0] == 0u) ? 1u : 0u;  // 1 => int64
}

__device__ __forceinline__ int load_idx(const int* __restrict__ ei,
                                        int logical, unsigned wide) {
    return ei[wide ? (logical << 1) : logical];
}

// ---------------- K1: h(bf16) = x @ W, fused a_src/a_dst ----------------
__global__ __launch_bounds__(256) void k_gemm(
    const float* __restrict__ x, const float* __restrict__ W,
    const float* __restrict__ att_s, const float* __restrict__ att_d,
    unsigned short* __restrict__ h16,
    float* __restrict__ a_s, float* __restrict__ a_d)
{
    __shared__ float Ws[256 * 32];
    __shared__ float xs[32 * 132];
    const int tid = threadIdx.x;

    #pragma unroll
    for (int i = 0; i < 8; ++i) {
        int idx = i * 1024 + tid * 4;
        *reinterpret_cast<float4*>(Ws + idx) =
            *reinterpret_cast<const float4*>(W + idx);
    }

    const int j4 = tid & 7;
    const int rl = tid >> 3;
    const int c0 = j4 * 4;
    const float4 avs = *reinterpret_cast<const float4*>(att_s + c0);
    const float4 avd = *reinterpret_cast<const float4*>(att_d + c0);

    for (int tile = blockIdx.x; tile < (NN / 32); tile += gridDim.x) {
        const int row0 = tile * 32;
        float4 acc = make_float4(0.f, 0.f, 0.f, 0.f);

        for (int kc = 0; kc < 256; kc += 128) {
            __syncthreads();
            #pragma unroll
            for (int i = 0; i < 4; ++i) {
                int l = i * 1024 + tid * 4;
                int r = l >> 7, c = l & 127;
                *reinterpret_cast<float4*>(xs + r * 132 + c) =
                    *reinterpret_cast<const float4*>(
                        x + (size_t)(row0 + r) * 256 + kc + c);
            }
            __syncthreads();
            const float* xr = xs + rl * 132;
            #pragma unroll 4
            for (int k0 = 0; k0 < 128; k0 += 4) {
                float4 xv = *reinterpret_cast<const float4*>(xr + k0);
                #pragma unroll
                for (int q = 0; q < 4; ++q) {
                    float xq = (q == 0) ? xv.x : (q == 1) ? xv.y
                             : (q == 2) ? xv.z : xv.w;
                    float4 wv = *reinterpret_cast<const float4*>(
                        Ws + (kc + k0 + q) * 32 + c0);
                    acc.x = fmaf(xq, wv.x, acc.x);
                    acc.y = fmaf(xq, wv.y, acc.y);
                    acc.z = fmaf(xq, wv.z, acc.z);
                    acc.w = fmaf(xq, wv.w, acc.w);
                }
            }
        }
        const int row = row0 + rl;
        ushort4 hb;
        hb.x = f2bf(acc.x); hb.y = f2bf(acc.y);
        hb.z = f2bf(acc.z); hb.w = f2bf(acc.w);
        *reinterpret_cast<ushort4*>(h16 + (size_t)row * 32 + c0) = hb;
        float v1 = acc.x * avs.x + acc.y * avs.y + acc.z * avs.z + acc.w * avs.w;
        float v2 = acc.x * avd.x + acc.y * avd.y + acc.z * avd.z + acc.w * avd.w;
        #pragma unroll
        for (int off = 4; off; off >>= 1) {
            v1 += __shfl_xor(v1, off, 8);
            v2 += __shfl_xor(v2, off, 8);
        }
        if (j4 == 0) { a_s[row] = v1; a_d[row] = v2; }
    }
}

// ---------------- K_A: global bucket histogram --------------------------
__global__ __launch_bounds__(256) void k_hist(
    const int* __restrict__ ei, const unsigned* __restrict__ flag,
    int* __restrict__ bhist)
{
    __shared__ int hl[NBKT];
    const int tid = threadIdx.x;
    for (int i = tid; i < NBKT; i += 256) hl[i] = 0;
    __syncthreads();
    const unsigned wide = *flag;
    const int base = blockIdx.x * 8192;
    #pragma unroll
    for (int k = 0; k < 32; ++k) {
        int e = base + k * 256 + tid;
        if (e < EE) {
            unsigned d = (unsigned)load_idx(ei, EE + e, wide);
            atomicAdd(&hl[d / DPB], 1);
        }
    }
    __syncthreads();
    for (int i = tid; i < NBKT; i += 256)
        if (hl[i]) atomicAdd(&bhist[i], hl[i]);
}

// ---------------- K_B: scan 512 bucket counts -> offs, gcursor ----------
__global__ __launch_bounds__(256) void k_scan(
    const int* __restrict__ bhist, int* __restrict__ offs,
    int* __restrict__ gcursor)
{
    __shared__ int pair[256];
    const int t = threadIdx.x;
    int a0 = bhist[2 * t], a1 = bhist[2 * t + 1];
    pair[t] = a0 + a1;
    __syncthreads();
    for (int off = 1; off < 256; off <<= 1) {
        int add = (t >= off) ? pair[t - off] : 0;
        __syncthreads();
        pair[t] += add;
        __syncthreads();
    }
    int excl = pair[t] - a0 - a1;
    offs[2 * t] = excl;           gcursor[2 * t] = excl;
    offs[2 * t + 1] = excl + a0;  gcursor[2 * t + 1] = excl + a0;
    if (t == 255) offs[NBKT] = pair[255];
}

// ---------------- K_C: multisplit scatter (coalesced writes) ------------
__global__ __launch_bounds__(256) void k_msplit(
    const int* __restrict__ ei, const unsigned* __restrict__ flag,
    int* __restrict__ gcursor, int2* __restrict__ packed)
{
    __shared__ int2 staged[RND];       // 48 KB
    __shared__ int hist[NBKT], base[NBKT], rcnt[NBKT], gposL[NBKT];
    __shared__ int pair[256];
    const int tid = threadIdx.x;
    const int chunk0 = blockIdx.x * RND;
    const unsigned wide = *flag;

    for (int i = tid; i < NBKT; i += 256) { hist[i] = 0; rcnt[i] = 0; }
    __syncthreads();
    #pragma unroll
    for (int k = 0; k < RND / 256; ++k) {
        int e = chunk0 + k * 256 + tid;
        if (e < EE) {
            unsigned d = (unsigned)load_idx(ei, EE + e, wide);
            atomicAdd(&hist[d / DPB], 1);
        }
    }
    __syncthreads();
    int h0 = hist[2 * tid], h1 = hist[2 * tid + 1];
    pair[tid] = h0 + h1;
    __syncthreads();
    for (int off = 1; off < 256; off <<= 1) {
        int add = (tid >= off) ? pair[tid - off] : 0;
        __syncthreads();
        pair[tid] += add;
        __syncthreads();
    }
    int excl = pair[tid] - h0 - h1;
    base[2 * tid] = excl;
    base[2 * tid + 1] = excl + h0;
    for (int b = tid; b < NBKT; b += 256) {
        int c = hist[b];
        if (c) gposL[b] = atomicAdd(&gcursor[b], c);
    }
    __syncthreads();
    #pragma unroll
    for (int k = 0; k < RND / 256; ++k) {
        int e = chunk0 + k * 256 + tid;
        if (e < EE) {
            int s = load_idx(ei, e, wide);
            int d = load_idx(ei, EE + e, wide);
            int b = (unsigned)d / DPB;
            int lp = base[b] + atomicAdd(&rcnt[b], 1);
            staged[lp] = make_int2(s, d);
        }
    }
    __syncthreads();
    int nv = EE - chunk0; if (nv > RND) nv = RND;
    for (int i = tid; i < nv; i += 256) {
        int2 ed = staged[i];
        int b = (unsigned)ed.y / DPB;
        packed[gposL[b] + (i - base[b])] = ed;
    }
}

// ---------------- K_D: bucket aggregate + full fused epilogue -----------
// 1024 threads/block: 16 waves -> 2 blocks/CU = 32 waves/CU (full slots).
__global__ __launch_bounds__(1024) void k_aggr(
    const int2* __restrict__ packed, const int* __restrict__ offs,
    const unsigned short* __restrict__ h16,
    const float* __restrict__ a_s, const float* __restrict__ a_d,
    const float* __restrict__ bias, float* __restrict__ out)
{
    __shared__ float accL[DPB * 33];   // stride 33: banks spread by node id
    __shared__ float denL[DPB];
    __shared__ float wselfL[DPB];
    const int tid = threadIdx.x;
    const int b = blockIdx.x;
    const int d0 = b * DPB;
    int cnt = NN - d0; if (cnt > DPB) cnt = DPB;
    if (cnt <= 0) return;

    for (int i = tid; i < DPB * 33; i += 1024) accL[i] = 0.f;
    if (tid < DPB) denL[tid] = 0.f;
    __syncthreads();

    const int e0 = offs[b], e1 = offs[b + 1];
    for (int i = e0 + tid; i < e1; i += 1024) {
        int2 ed = packed[i];
        const int s = ed.x, dd = ed.y;
        float al = a_s[s] + a_d[dd];
        al = (al >= 0.f) ? al : 0.2f * al;
        float w = __expf(al);
        const int nl = dd - d0;
        atomicAdd(&denL[nl], w);
        const uint4* hp = reinterpret_cast<const uint4*>(h16 + (size_t)s * 32);
        uint4 r0 = hp[0], r1 = hp[1], r2 = hp[2], r3 = hp[3];
        float* arow = accL + nl * 33;
#define DO(u, q) \
        atomicAdd(arow + 2*(q),     w * __uint_as_float((u) << 16)); \
        atomicAdd(arow + 2*(q) + 1, w * __uint_as_float((u) & 0xffff0000u));
        DO(r0.x, 0) DO(r0.y, 1) DO(r0.z, 2) DO(r0.w, 3)
        DO(r1.x, 4) DO(r1.y, 5) DO(r1.z, 6) DO(r1.w, 7)
        DO(r2.x, 8) DO(r2.y, 9) DO(r2.z, 10) DO(r2.w, 11)
        DO(r3.x, 12) DO(r3.y, 13) DO(r3.z, 14) DO(r3.w, 15)
#undef DO
    }
    __syncthreads();
    if (tid < DPB && tid < cnt) {
        int d = d0 + tid;
        float al = a_s[d] + a_d[d];
        al = (al >= 0.f) ? al : 0.2f * al;
        float w = __expf(al);
        wselfL[tid] = w;
        denL[tid] += w;
    }
    __syncthreads();
    for (int idx = tid; idx < cnt * 32; idx += 1024) {
        int n = idx >> 5, c = idx & 31;
        int d = d0 + n;
        float hv = bf2f(h16[(size_t)d * 32 + c]);
        float v = (accL[n * 33 + c] + wselfL[n] * hv) / denL[n];
        v = fmaxf(v + bias[c], 0.f);
        int t = d * 32 + c;
        unsigned y0, y1;
        threefry2x32_01(0u, (unsigned)t, y0, y1);
        out[t] = ((y0 ^ y1) >> 31) ? 0.f : v * 2.f;
    }
}

extern "C" void kernel_launch(void* const* d_in, const int* in_sizes, int n_in,
                              void* d_out, int out_size, void* d_ws, size_t ws_size,
                              hipStream_t stream) {
    const float* x     = (const float*)d_in[0];
    const float* W     = (const float*)d_in[1];
    const float* att_s = (const float*)d_in[2];
    const float* att_d = (const float*)d_in[3];
    const float* bias  = (const float*)d_in[4];
    const int*   ei    = (const int*)d_in[5];
    float* out = (float*)d_out;

    int2* packed = (int2*)d_ws;
    unsigned short* h16 = (unsigned short*)(packed + EE);
    float* a_s = (float*)(h16 + (size_t)NN * FO);
    float* a_d = a_s + NN;
    int* bhist = (int*)(a_d + NN);
    int* offs = bhist + NBKT;
    int* gcursor = offs + (NBKT + 1);
    unsigned* flag = (unsigned*)(gcursor + NBKT);

    hipMemsetAsync(bhist, 0, NBKT * sizeof(int), stream);

    k_detect<<<1, 256, 0, stream>>>((const unsigned*)ei, flag);
    k_gemm<<<1024, 256, 0, stream>>>(x, W, att_s, att_d, h16, a_s, a_d);
    k_hist<<<(EE + 8191) / 8192, 256, 0, stream>>>(ei, flag, bhist);
    k_scan<<<1, 256, 0, stream>>>(bhist, offs, gcursor);
    k_msplit<<<(EE + RND - 1) / RND, 256, 0, stream>>>(ei, flag, gcursor, packed);
    k_aggr<<<(NN + DPB - 1) / DPB, 1024, 0, stream>>>(packed, offs, h16, a_s, a_d, bias, out);
}

// Round 6
// 206.080 us; speedup vs baseline: 1.8550x; 1.8509x over previous
//
#include <hip/hip_runtime.h>

#define NN 100000
#define EE 1600000
#define FO 32
#define NBKT 512
#define DPB 196            // dst nodes per bucket; NBKT*DPB = 100352 >= NN
#define RND 6144           // edges per multisplit block (LDS staging 48KB)
#define LCAP 8192          // per-bucket edge capacity in k_aggr LDS (32KB)

// ---------------- threefry2x32 with key (0,1) = jax.random.key(1) -------
__device__ __forceinline__ unsigned rotl32(unsigned x, unsigned r) {
    return (x << r) | (x >> (32u - r));
}

__device__ __forceinline__ void threefry2x32_01(unsigned x0, unsigned x1,
                                                unsigned& y0, unsigned& y1) {
    const unsigned ks0 = 0u, ks1 = 1u, ks2 = 0x1BD11BDBu;
    x0 += ks0; x1 += ks1;
#define TF_R(r) { x0 += x1; x1 = rotl32(x1, (r)); x1 ^= x0; }
    TF_R(13) TF_R(15) TF_R(26) TF_R(6)   x0 += ks1; x1 += ks2 + 1u;
    TF_R(17) TF_R(29) TF_R(16) TF_R(24)  x0 += ks2; x1 += ks0 + 2u;
    TF_R(13) TF_R(15) TF_R(26) TF_R(6)   x0 += ks0; x1 += ks1 + 3u;
    TF_R(17) TF_R(29) TF_R(16) TF_R(24)  x0 += ks1; x1 += ks2 + 4u;
    TF_R(13) TF_R(15) TF_R(26) TF_R(6)   x0 += ks2; x1 += ks0 + 5u;
#undef TF_R
    y0 = x0; y1 = x1;
}

__device__ __forceinline__ unsigned short f2bf(float f) {   // RNE
    unsigned u = __float_as_uint(f);
    unsigned r = (u + 0x7fffu + ((u >> 16) & 1u)) >> 16;
    return (unsigned short)r;
}
__device__ __forceinline__ float bf2f(unsigned short b) {
    return __uint_as_float(((unsigned)b) << 16);
}

// ---------------- K0: detect edge_index storage width -------------------
__global__ __launch_bounds__(256) void k_detect(const unsigned* __restrict__ ei,
                                                unsigned* __restrict__ flag) {
    __shared__ unsigned red[256];
    unsigned v = 0;
    for (int i = threadIdx.x; i < 4096; i += 256) v |= ei[2 * i + 1];
    red[threadIdx.x] = v;
    __syncthreads();
    for (int s = 128; s; s >>= 1) {
        if (threadIdx.x < s) red[threadIdx.x] |= red[threadIdx.x + s];
        __syncthreads();
    }
    if (threadIdx.x == 0) *flag = (red[0] == 0u) ? 1u : 0u;  // 1 => int64
}

__device__ __forceinline__ int load_idx(const int* __restrict__ ei,
                                        int logical, unsigned wide) {
    return ei[wide ? (logical << 1) : logical];
}

// ---------------- K1: h(bf16) = x @ W, fused a_src/a_dst ----------------
__global__ __launch_bounds__(256) void k_gemm(
    const float* __restrict__ x, const float* __restrict__ W,
    const float* __restrict__ att_s, const float* __restrict__ att_d,
    unsigned short* __restrict__ h16,
    float* __restrict__ a_s, float* __restrict__ a_d)
{
    __shared__ float Ws[256 * 32];
    __shared__ float xs[32 * 132];
    const int tid = threadIdx.x;

    #pragma unroll
    for (int i = 0; i < 8; ++i) {
        int idx = i * 1024 + tid * 4;
        *reinterpret_cast<float4*>(Ws + idx) =
            *reinterpret_cast<const float4*>(W + idx);
    }

    const int j4 = tid & 7;
    const int rl = tid >> 3;
    const int c0 = j4 * 4;
    const float4 avs = *reinterpret_cast<const float4*>(att_s + c0);
    const float4 avd = *reinterpret_cast<const float4*>(att_d + c0);

    for (int tile = blockIdx.x; tile < (NN / 32); tile += gridDim.x) {
        const int row0 = tile * 32;
        float4 acc = make_float4(0.f, 0.f, 0.f, 0.f);

        for (int kc = 0; kc < 256; kc += 128) {
            __syncthreads();
            #pragma unroll
            for (int i = 0; i < 4; ++i) {
                int l = i * 1024 + tid * 4;
                int r = l >> 7, c = l & 127;
                *reinterpret_cast<float4*>(xs + r * 132 + c) =
                    *reinterpret_cast<const float4*>(
                        x + (size_t)(row0 + r) * 256 + kc + c);
            }
            __syncthreads();
            const float* xr = xs + rl * 132;
            #pragma unroll 4
            for (int k0 = 0; k0 < 128; k0 += 4) {
                float4 xv = *reinterpret_cast<const float4*>(xr + k0);
                #pragma unroll
                for (int q = 0; q < 4; ++q) {
                    float xq = (q == 0) ? xv.x : (q == 1) ? xv.y
                             : (q == 2) ? xv.z : xv.w;
                    float4 wv = *reinterpret_cast<const float4*>(
                        Ws + (kc + k0 + q) * 32 + c0);
                    acc.x = fmaf(xq, wv.x, acc.x);
                    acc.y = fmaf(xq, wv.y, acc.y);
                    acc.z = fmaf(xq, wv.z, acc.z);
                    acc.w = fmaf(xq, wv.w, acc.w);
                }
            }
        }
        const int row = row0 + rl;
        ushort4 hb;
        hb.x = f2bf(acc.x); hb.y = f2bf(acc.y);
        hb.z = f2bf(acc.z); hb.w = f2bf(acc.w);
        *reinterpret_cast<ushort4*>(h16 + (size_t)row * 32 + c0) = hb;
        float v1 = acc.x * avs.x + acc.y * avs.y + acc.z * avs.z + acc.w * avs.w;
        float v2 = acc.x * avd.x + acc.y * avd.y + acc.z * avd.z + acc.w * avd.w;
        #pragma unroll
        for (int off = 4; off; off >>= 1) {
            v1 += __shfl_xor(v1, off, 8);
            v2 += __shfl_xor(v2, off, 8);
        }
        if (j4 == 0) { a_s[row] = v1; a_d[row] = v2; }
    }
}

// ---------------- K_deg: per-node degree (global atomics) ---------------
__global__ __launch_bounds__(256) void k_deg(
    const int* __restrict__ ei, const unsigned* __restrict__ flag,
    int* __restrict__ deg)
{
    int e = blockIdx.x * 256 + threadIdx.x;
    if (e >= EE) return;
    const unsigned wide = *flag;
    atomicAdd(&deg[load_idx(ei, EE + e, wide)], 1);
}

// ---------------- scan deg -> offs (exclusive), 100K elements -----------
__global__ __launch_bounds__(1024) void k_scanA(
    const int* __restrict__ deg, int* __restrict__ inc, int* __restrict__ btot)
{
    __shared__ int s[1024];
    int g = blockIdx.x * 1024 + threadIdx.x;
    int v = (g < NN) ? deg[g] : 0;
    s[threadIdx.x] = v;
    __syncthreads();
    for (int off = 1; off < 1024; off <<= 1) {
        int add = (threadIdx.x >= off) ? s[threadIdx.x - off] : 0;
        __syncthreads();
        s[threadIdx.x] += add;
        __syncthreads();
    }
    if (g < NN) inc[g] = s[threadIdx.x];
    if (threadIdx.x == 1023) btot[blockIdx.x] = s[1023];
}

__global__ __launch_bounds__(128) void k_scanB(int* __restrict__ btot)
{
    __shared__ int s[128];
    int v = (threadIdx.x < 98) ? btot[threadIdx.x] : 0;
    s[threadIdx.x] = v;
    __syncthreads();
    for (int off = 1; off < 128; off <<= 1) {
        int add = (threadIdx.x >= off) ? s[threadIdx.x - off] : 0;
        __syncthreads();
        s[threadIdx.x] += add;
        __syncthreads();
    }
    if (threadIdx.x < 98) btot[threadIdx.x] = s[threadIdx.x] - v;  // exclusive
}

__global__ __launch_bounds__(1024) void k_scanC(
    const int* __restrict__ deg, int* __restrict__ inc /*-> offs*/,
    const int* __restrict__ btot)
{
    int g = blockIdx.x * 1024 + threadIdx.x;
    if (g >= NN) return;
    inc[g] = inc[g] - deg[g] + btot[blockIdx.x];
}

// ---------------- K_binit: bucket cursors from offs ---------------------
__global__ __launch_bounds__(512) void k_binit(
    int* __restrict__ offs, int* __restrict__ gcursor)
{
    int b = threadIdx.x;
    if (b == 0) offs[NN] = EE;
    long idx = (long)b * DPB;
    gcursor[b] = (idx >= NN) ? EE : offs[idx];
}

// ---------------- K_C: multisplit scatter (coalesced writes) ------------
__global__ __launch_bounds__(256) void k_msplit(
    const int* __restrict__ ei, const unsigned* __restrict__ flag,
    int* __restrict__ gcursor, int2* __restrict__ packed)
{
    __shared__ int2 staged[RND];       // 48 KB
    __shared__ int hist[NBKT], base[NBKT], rcnt[NBKT], gposL[NBKT];
    __shared__ int pair[256];
    const int tid = threadIdx.x;
    const int chunk0 = blockIdx.x * RND;
    const unsigned wide = *flag;

    for (int i = tid; i < NBKT; i += 256) { hist[i] = 0; rcnt[i] = 0; }
    __syncthreads();
    #pragma unroll
    for (int k = 0; k < RND / 256; ++k) {
        int e = chunk0 + k * 256 + tid;
        if (e < EE) {
            unsigned d = (unsigned)load_idx(ei, EE + e, wide);
            atomicAdd(&hist[d / DPB], 1);
        }
    }
    __syncthreads();
    int h0 = hist[2 * tid], h1 = hist[2 * tid + 1];
    pair[tid] = h0 + h1;
    __syncthreads();
    for (int off = 1; off < 256; off <<= 1) {
        int add = (tid >= off) ? pair[tid - off] : 0;
        __syncthreads();
        pair[tid] += add;
        __syncthreads();
    }
    int excl = pair[tid] - h0 - h1;
    base[2 * tid] = excl;
    base[2 * tid + 1] = excl + h0;
    for (int b = tid; b < NBKT; b += 256) {
        int c = hist[b];
        if (c) gposL[b] = atomicAdd(&gcursor[b], c);
    }
    __syncthreads();
    #pragma unroll
    for (int k = 0; k < RND / 256; ++k) {
        int e = chunk0 + k * 256 + tid;
        if (e < EE) {
            int s = load_idx(ei, e, wide);
            int d = load_idx(ei, EE + e, wide);
            int b = (unsigned)d / DPB;
            int lp = base[b] + atomicAdd(&rcnt[b], 1);
            staged[lp] = make_int2(s, d);
        }
    }
    __syncthreads();
    int nv = EE - chunk0; if (nv > RND) nv = RND;
    for (int i = tid; i < nv; i += 256) {
        int2 ed = staged[i];
        int b = (unsigned)ed.y / DPB;
        packed[gposL[b] + (i - base[b])] = ed;
    }
}

// ---------------- K_D: LDS counting-sort + atomic-free aggregate --------
// Block = bucket (196 nodes). Phase A: sort edges by exact dst into LDS
// (1 LDS atomic per edge). Phase B: one 32-lane half-wave per node, lane j
// owns column j; register accumulation, zero atomics; fused epilogue.
__global__ __launch_bounds__(1024) void k_aggr(
    const int2* __restrict__ packed, const int* __restrict__ offs,
    const unsigned short* __restrict__ h16,
    const float* __restrict__ a_s, const float* __restrict__ a_d,
    const float* __restrict__ bias, float* __restrict__ out)
{
    __shared__ int srt[LCAP];          // 32 KB
    __shared__ int cur[DPB];
    const int tid = threadIdx.x;
    const int b = blockIdx.x;
    const int d0 = b * DPB;
    int cnt = NN - d0; if (cnt > DPB) cnt = DPB;
    const int segbase = offs[d0];
    const int segend  = offs[d0 + cnt];
    const int m = segend - segbase;

    if (tid < cnt) cur[tid] = offs[d0 + tid] - segbase;
    __syncthreads();
    for (int i = tid; i < m; i += 1024) {
        int2 ed = packed[segbase + i];
        int pos = atomicAdd(&cur[ed.y - d0], 1);
        if (pos < LCAP) srt[pos] = ed.x;
    }
    __syncthreads();
    // after sort, cur[nl] == end of node nl's segment (local coords)
    const int hw = tid >> 5;           // half-wave 0..31
    const int j  = tid & 31;           // column
    for (int nl = hw; nl < cnt; nl += 32) {
        const int d = d0 + nl;
        const float ad = a_d[d];
        const int e0 = (nl == 0) ? 0 : cur[nl - 1];
        const int e1 = cur[nl];
        float acc = 0.f, den = 0.f;
        int i = e0;
        for (; i + 1 < e1; i += 2) {   // unroll-2 for MLP
            int s1 = srt[i], s2 = srt[i + 1];
            float al1 = a_s[s1] + ad;
            float al2 = a_s[s2] + ad;
            float hv1 = bf2f(h16[(size_t)s1 * 32 + j]);
            float hv2 = bf2f(h16[(size_t)s2 * 32 + j]);
            al1 = (al1 >= 0.f) ? al1 : 0.2f * al1;
            al2 = (al2 >= 0.f) ? al2 : 0.2f * al2;
            float w1 = __expf(al1), w2 = __expf(al2);
            acc = fmaf(w1, hv1, acc); den += w1;
            acc = fmaf(w2, hv2, acc); den += w2;
        }
        if (i < e1) {
            int s1 = srt[i];
            float al1 = a_s[s1] + ad;
            al1 = (al1 >= 0.f) ? al1 : 0.2f * al1;
            float w1 = __expf(al1);
            acc = fmaf(w1, bf2f(h16[(size_t)s1 * 32 + j]), acc); den += w1;
        }
        // self-loop
        float al = a_s[d] + ad;
        al = (al >= 0.f) ? al : 0.2f * al;
        float w = __expf(al);
        acc = fmaf(w, bf2f(h16[(size_t)d * 32 + j]), acc); den += w;
        // epilogue: /den + bias + relu + threefry dropout
        float v = fmaxf(acc / den + bias[j], 0.f);
        int t = d * 32 + j;
        unsigned y0, y1;
        threefry2x32_01(0u, (unsigned)t, y0, y1);
        out[t] = ((y0 ^ y1) >> 31) ? 0.f : v * 2.f;
    }
}

extern "C" void kernel_launch(void* const* d_in, const int* in_sizes, int n_in,
                              void* d_out, int out_size, void* d_ws, size_t ws_size,
                              hipStream_t stream) {
    const float* x     = (const float*)d_in[0];
    const float* W     = (const float*)d_in[1];
    const float* att_s = (const float*)d_in[2];
    const float* att_d = (const float*)d_in[3];
    const float* bias  = (const float*)d_in[4];
    const int*   ei    = (const int*)d_in[5];
    float* out = (float*)d_out;

    // ws: packed[EE] int2 | h16[NN*32] bf16 | a_s[NN] | a_d[NN] | deg[NN]
    //     | offs[NN+1] | gcursor[512] | btot[128] | flag
    int2* packed = (int2*)d_ws;
    unsigned short* h16 = (unsigned short*)(packed + EE);
    float* a_s = (float*)(h16 + (size_t)NN * FO);
    float* a_d = a_s + NN;
    int* deg = (int*)(a_d + NN);
    int* offs = deg + NN;
    int* gcursor = offs + (NN + 1);
    int* btot = gcursor + NBKT;
    unsigned* flag = (unsigned*)(btot + 128);

    hipMemsetAsync(deg, 0, (size_t)NN * sizeof(int), stream);

    k_detect<<<1, 256, 0, stream>>>((const unsigned*)ei, flag);
    k_gemm<<<1024, 256, 0, stream>>>(x, W, att_s, att_d, h16, a_s, a_d);
    k_deg<<<(EE + 255) / 256, 256, 0, stream>>>(ei, flag, deg);
    k_scanA<<<98, 1024, 0, stream>>>(deg, offs, btot);
    k_scanB<<<1, 128, 0, stream>>>(btot);
    k_scanC<<<98, 1024, 0, stream>>>(deg, offs, btot);
    k_binit<<<1, 512, 0, stream>>>(offs, gcursor);
    k_msplit<<<(EE + RND - 1) / RND, 256, 0, stream>>>(ei, flag, gcursor, packed);
    k_aggr<<<(NN + DPB - 1) / DPB, 1024, 0, stream>>>(packed, offs, h16, a_s, a_d, bias, out);
}

// Round 7
// 147.957 us; speedup vs baseline: 2.5837x; 1.3928x over previous
//
#include <hip/hip_runtime.h>

#define NN 100000
#define EE 1600000
#define FO 32
#define NBKT 512
#define DPB 196            // dst nodes per bucket; NBKT*DPB = 100352 >= NN
#define RND 6144           // edges per multisplit block (LDS staging 48KB)
#define LCAP 8192          // per-bucket edge capacity in k_aggr LDS (32KB)

// ---------------- threefry2x32 with key (0,1) = jax.random.key(1) -------
__device__ __forceinline__ unsigned rotl32(unsigned x, unsigned r) {
    return (x << r) | (x >> (32u - r));
}

__device__ __forceinline__ void threefry2x32_01(unsigned x0, unsigned x1,
                                                unsigned& y0, unsigned& y1) {
    const unsigned ks0 = 0u, ks1 = 1u, ks2 = 0x1BD11BDBu;
    x0 += ks0; x1 += ks1;
#define TF_R(r) { x0 += x1; x1 = rotl32(x1, (r)); x1 ^= x0; }
    TF_R(13) TF_R(15) TF_R(26) TF_R(6)   x0 += ks1; x1 += ks2 + 1u;
    TF_R(17) TF_R(29) TF_R(16) TF_R(24)  x0 += ks2; x1 += ks0 + 2u;
    TF_R(13) TF_R(15) TF_R(26) TF_R(6)   x0 += ks0; x1 += ks1 + 3u;
    TF_R(17) TF_R(29) TF_R(16) TF_R(24)  x0 += ks1; x1 += ks2 + 4u;
    TF_R(13) TF_R(15) TF_R(26) TF_R(6)   x0 += ks2; x1 += ks0 + 5u;
#undef TF_R
    y0 = x0; y1 = x1;
}

__device__ __forceinline__ unsigned short f2bf(float f) {   // RNE
    unsigned u = __float_as_uint(f);
    unsigned r = (u + 0x7fffu + ((u >> 16) & 1u)) >> 16;
    return (unsigned short)r;
}
__device__ __forceinline__ float bf2f(unsigned short b) {
    return __uint_as_float(((unsigned)b) << 16);
}

// ---------------- K0: detect edge_index storage width -------------------
__global__ __launch_bounds__(256) void k_detect(const unsigned* __restrict__ ei,
                                                unsigned* __restrict__ flag) {
    __shared__ unsigned red[256];
    unsigned v = 0;
    for (int i = threadIdx.x; i < 4096; i += 256) v |= ei[2 * i + 1];
    red[threadIdx.x] = v;
    __syncthreads();
    for (int s = 128; s; s >>= 1) {
        if (threadIdx.x < s) red[threadIdx.x] |= red[threadIdx.x + s];
        __syncthreads();
    }
    if (threadIdx.x == 0) *flag = (red[0] == 0u) ? 1u : 0u;  // 1 => int64
}

__device__ __forceinline__ int load_idx(const int* __restrict__ ei,
                                        int logical, unsigned wide) {
    return ei[wide ? (logical << 1) : logical];
}

// ---------------- K1: h(bf16) = x @ W, fused a_src/a_dst ----------------
__global__ __launch_bounds__(256) void k_gemm(
    const float* __restrict__ x, const float* __restrict__ W,
    const float* __restrict__ att_s, const float* __restrict__ att_d,
    unsigned short* __restrict__ h16,
    float* __restrict__ a_s, float* __restrict__ a_d)
{
    __shared__ float Ws[256 * 32];
    __shared__ float xs[32 * 132];
    const int tid = threadIdx.x;

    #pragma unroll
    for (int i = 0; i < 8; ++i) {
        int idx = i * 1024 + tid * 4;
        *reinterpret_cast<float4*>(Ws + idx) =
            *reinterpret_cast<const float4*>(W + idx);
    }

    const int j4 = tid & 7;
    const int rl = tid >> 3;
    const int c0 = j4 * 4;
    const float4 avs = *reinterpret_cast<const float4*>(att_s + c0);
    const float4 avd = *reinterpret_cast<const float4*>(att_d + c0);

    for (int tile = blockIdx.x; tile < (NN / 32); tile += gridDim.x) {
        const int row0 = tile * 32;
        float4 acc = make_float4(0.f, 0.f, 0.f, 0.f);

        for (int kc = 0; kc < 256; kc += 128) {
            __syncthreads();
            #pragma unroll
            for (int i = 0; i < 4; ++i) {
                int l = i * 1024 + tid * 4;
                int r = l >> 7, c = l & 127;
                *reinterpret_cast<float4*>(xs + r * 132 + c) =
                    *reinterpret_cast<const float4*>(
                        x + (size_t)(row0 + r) * 256 + kc + c);
            }
            __syncthreads();
            const float* xr = xs + rl * 132;
            #pragma unroll 4
            for (int k0 = 0; k0 < 128; k0 += 4) {
                float4 xv = *reinterpret_cast<const float4*>(xr + k0);
                #pragma unroll
                for (int q = 0; q < 4; ++q) {
                    float xq = (q == 0) ? xv.x : (q == 1) ? xv.y
                             : (q == 2) ? xv.z : xv.w;
                    float4 wv = *reinterpret_cast<const float4*>(
                        Ws + (kc + k0 + q) * 32 + c0);
                    acc.x = fmaf(xq, wv.x, acc.x);
                    acc.y = fmaf(xq, wv.y, acc.y);
                    acc.z = fmaf(xq, wv.z, acc.z);
                    acc.w = fmaf(xq, wv.w, acc.w);
                }
            }
        }
        const int row = row0 + rl;
        ushort4 hb;
        hb.x = f2bf(acc.x); hb.y = f2bf(acc.y);
        hb.z = f2bf(acc.z); hb.w = f2bf(acc.w);
        *reinterpret_cast<ushort4*>(h16 + (size_t)row * 32 + c0) = hb;
        float v1 = acc.x * avs.x + acc.y * avs.y + acc.z * avs.z + acc.w * avs.w;
        float v2 = acc.x * avd.x + acc.y * avd.y + acc.z * avd.z + acc.w * avd.w;
        #pragma unroll
        for (int off = 4; off; off >>= 1) {
            v1 += __shfl_xor(v1, off, 8);
            v2 += __shfl_xor(v2, off, 8);
        }
        if (j4 == 0) { a_s[row] = v1; a_d[row] = v2; }
    }
}

// ---------------- K_A: global bucket histogram (LDS-staged) -------------
__global__ __launch_bounds__(256) void k_hist(
    const int* __restrict__ ei, const unsigned* __restrict__ flag,
    int* __restrict__ bhist)
{
    __shared__ int hl[NBKT];
    const int tid = threadIdx.x;
    for (int i = tid; i < NBKT; i += 256) hl[i] = 0;
    __syncthreads();
    const unsigned wide = *flag;
    const int base = blockIdx.x * 8192;
    #pragma unroll
    for (int k = 0; k < 32; ++k) {
        int e = base + k * 256 + tid;
        if (e < EE) {
            unsigned d = (unsigned)load_idx(ei, EE + e, wide);
            atomicAdd(&hl[d / DPB], 1);
        }
    }
    __syncthreads();
    for (int i = tid; i < NBKT; i += 256)
        if (hl[i]) atomicAdd(&bhist[i], hl[i]);
}

// ---------------- K_B: scan 512 bucket counts -> boffs, gcursor ---------
__global__ __launch_bounds__(256) void k_scan(
    const int* __restrict__ bhist, int* __restrict__ boffs,
    int* __restrict__ gcursor)
{
    __shared__ int pair[256];
    const int t = threadIdx.x;
    int a0 = bhist[2 * t], a1 = bhist[2 * t + 1];
    pair[t] = a0 + a1;
    __syncthreads();
    for (int off = 1; off < 256; off <<= 1) {
        int add = (t >= off) ? pair[t - off] : 0;
        __syncthreads();
        pair[t] += add;
        __syncthreads();
    }
    int excl = pair[t] - a0 - a1;
    boffs[2 * t] = excl;           gcursor[2 * t] = excl;
    boffs[2 * t + 1] = excl + a0;  gcursor[2 * t + 1] = excl + a0;
    if (t == 255) boffs[NBKT] = pair[255];
}

// ---------------- K_C: multisplit scatter (coalesced writes) ------------
__global__ __launch_bounds__(256) void k_msplit(
    const int* __restrict__ ei, const unsigned* __restrict__ flag,
    int* __restrict__ gcursor, int2* __restrict__ packed)
{
    __shared__ int2 staged[RND];       // 48 KB
    __shared__ int hist[NBKT], base[NBKT], rcnt[NBKT], gposL[NBKT];
    __shared__ int pair[256];
    const int tid = threadIdx.x;
    const int chunk0 = blockIdx.x * RND;
    const unsigned wide = *flag;

    for (int i = tid; i < NBKT; i += 256) { hist[i] = 0; rcnt[i] = 0; }
    __syncthreads();
    #pragma unroll
    for (int k = 0; k < RND / 256; ++k) {
        int e = chunk0 + k * 256 + tid;
        if (e < EE) {
            unsigned d = (unsigned)load_idx(ei, EE + e, wide);
            atomicAdd(&hist[d / DPB], 1);
        }
    }
    __syncthreads();
    int h0 = hist[2 * tid], h1 = hist[2 * tid + 1];
    pair[tid] = h0 + h1;
    __syncthreads();
    for (int off = 1; off < 256; off <<= 1) {
        int add = (tid >= off) ? pair[tid - off] : 0;
        __syncthreads();
        pair[tid] += add;
        __syncthreads();
    }
    int excl = pair[tid] - h0 - h1;
    base[2 * tid] = excl;
    base[2 * tid + 1] = excl + h0;
    for (int b = tid; b < NBKT; b += 256) {
        int c = hist[b];
        if (c) gposL[b] = atomicAdd(&gcursor[b], c);
    }
    __syncthreads();
    #pragma unroll
    for (int k = 0; k < RND / 256; ++k) {
        int e = chunk0 + k * 256 + tid;
        if (e < EE) {
            int s = load_idx(ei, e, wide);
            int d = load_idx(ei, EE + e, wide);
            int b = (unsigned)d / DPB;
            int lp = base[b] + atomicAdd(&rcnt[b], 1);
            staged[lp] = make_int2(s, d);
        }
    }
    __syncthreads();
    int nv = EE - chunk0; if (nv > RND) nv = RND;
    for (int i = tid; i < nv; i += 256) {
        int2 ed = staged[i];
        int b = (unsigned)ed.y / DPB;
        packed[gposL[b] + (i - base[b])] = ed;
    }
}

// ---------------- K_D: self-contained bucket sort + aggregate -----------
// Pass 1: count 196 node degrees in LDS. Block scan -> segment starts.
// Pass 2: place edges sorted-by-dst into LDS. Then atomic-free register
// aggregation (one 32-lane half-wave per node) + fused epilogue.
__global__ __launch_bounds__(1024) void k_aggr(
    const int2* __restrict__ packed, const int* __restrict__ boffs,
    const unsigned short* __restrict__ h16,
    const float* __restrict__ a_s, const float* __restrict__ a_d,
    const float* __restrict__ bias, float* __restrict__ out)
{
    __shared__ int srt[LCAP];          // 32 KB
    __shared__ int cntL[DPB];
    __shared__ int cur[DPB];
    __shared__ int sc[256];
    const int tid = threadIdx.x;
    const int b = blockIdx.x;
    const int d0 = b * DPB;
    int cnt = NN - d0; if (cnt > DPB) cnt = DPB;
    if (cnt <= 0) return;
    const int gb0 = boffs[b], gb1 = boffs[b + 1];
    const int m = gb1 - gb0;

    if (tid < DPB) cntL[tid] = 0;
    __syncthreads();
    for (int i = tid; i < m; i += 1024)                 // pass 1: degrees
        atomicAdd(&cntL[packed[gb0 + i].y - d0], 1);
    __syncthreads();
    if (tid < 256) sc[tid] = (tid < cnt) ? cntL[tid] : 0;
    __syncthreads();
    for (int off = 1; off < 256; off <<= 1) {           // Hillis-Steele
        int add = (tid < 256 && tid >= off) ? sc[tid - off] : 0;
        __syncthreads();
        if (tid < 256) sc[tid] += add;
        __syncthreads();
    }
    if (tid < cnt) cur[tid] = sc[tid] - cntL[tid];      // exclusive start
    __syncthreads();
    for (int i = tid; i < m; i += 1024) {               // pass 2: place
        int2 ed = packed[gb0 + i];
        int pos = atomicAdd(&cur[ed.y - d0], 1);
        if (pos < LCAP) srt[pos] = ed.x;
    }
    __syncthreads();
    // cur[nl] == end of node nl's local segment
    const int hw = tid >> 5;
    const int j  = tid & 31;
    for (int nl = hw; nl < cnt; nl += 32) {
        const int d = d0 + nl;
        const float ad = a_d[d];
        const int e0 = (nl == 0) ? 0 : cur[nl - 1];
        const int e1 = cur[nl];
        float acc = 0.f, den = 0.f;
        int i = e0;
        for (; i + 1 < e1; i += 2) {                    // unroll-2 for MLP
            int s1 = srt[i], s2 = srt[i + 1];
            float al1 = a_s[s1] + ad;
            float al2 = a_s[s2] + ad;
            float hv1 = bf2f(h16[(size_t)s1 * 32 + j]);
            float hv2 = bf2f(h16[(size_t)s2 * 32 + j]);
            al1 = (al1 >= 0.f) ? al1 : 0.2f * al1;
            al2 = (al2 >= 0.f) ? al2 : 0.2f * al2;
            float w1 = __expf(al1), w2 = __expf(al2);
            acc = fmaf(w1, hv1, acc); den += w1;
            acc = fmaf(w2, hv2, acc); den += w2;
        }
        if (i < e1) {
            int s1 = srt[i];
            float al1 = a_s[s1] + ad;
            al1 = (al1 >= 0.f) ? al1 : 0.2f * al1;
            float w1 = __expf(al1);
            acc = fmaf(w1, bf2f(h16[(size_t)s1 * 32 + j]), acc); den += w1;
        }
        float al = a_s[d] + ad;                         // self-loop
        al = (al >= 0.f) ? al : 0.2f * al;
        float w = __expf(al);
        acc = fmaf(w, bf2f(h16[(size_t)d * 32 + j]), acc); den += w;
        float v = fmaxf(acc / den + bias[j], 0.f);      // fused epilogue
        int t = d * 32 + j;
        unsigned y0, y1;
        threefry2x32_01(0u, (unsigned)t, y0, y1);
        out[t] = ((y0 ^ y1) >> 31) ? 0.f : v * 2.f;
    }
}

extern "C" void kernel_launch(void* const* d_in, const int* in_sizes, int n_in,
                              void* d_out, int out_size, void* d_ws, size_t ws_size,
                              hipStream_t stream) {
    const float* x     = (const float*)d_in[0];
    const float* W     = (const float*)d_in[1];
    const float* att_s = (const float*)d_in[2];
    const float* att_d = (const float*)d_in[3];
    const float* bias  = (const float*)d_in[4];
    const int*   ei    = (const int*)d_in[5];
    float* out = (float*)d_out;

    // ws: packed[EE] int2 | h16[NN*32] bf16 | a_s[NN] | a_d[NN]
    //     | bhist[512] | boffs[513] | gcursor[512] | flag
    int2* packed = (int2*)d_ws;
    unsigned short* h16 = (unsigned short*)(packed + EE);
    float* a_s = (float*)(h16 + (size_t)NN * FO);
    float* a_d = a_s + NN;
    int* bhist = (int*)(a_d + NN);
    int* boffs = bhist + NBKT;
    int* gcursor = boffs + (NBKT + 1);
    unsigned* flag = (unsigned*)(gcursor + NBKT);

    hipMemsetAsync(bhist, 0, NBKT * sizeof(int), stream);

    k_detect<<<1, 256, 0, stream>>>((const unsigned*)ei, flag);
    k_gemm<<<1024, 256, 0, stream>>>(x, W, att_s, att_d, h16, a_s, a_d);
    k_hist<<<(EE + 8191) / 8192, 256, 0, stream>>>(ei, flag, bhist);
    k_scan<<<1, 256, 0, stream>>>(bhist, boffs, gcursor);
    k_msplit<<<(EE + RND - 1) / RND, 256, 0, stream>>>(ei, flag, gcursor, packed);
    k_aggr<<<(NN + DPB - 1) / DPB, 1024, 0, stream>>>(packed, boffs, h16, a_s, a_d, bias, out);
}

// Round 8
// 145.335 us; speedup vs baseline: 2.6303x; 1.0180x over previous
//
#include <hip/hip_runtime.h>

#define NN 100000
#define EE 1600000
#define FO 32
#define NBKT 512
#define DPB 196            // dst nodes per bucket; NBKT*DPB = 100352 >= NN
#define RND 6144           // edges per multisplit block (LDS staging 48KB)
#define LCAP 8192          // per-bucket edge capacity in k_aggr LDS (32KB)
#define GROWS 128          // k_gemm rows per block
#define XPAD 68            // xs row stride (words): 16B-aligned, conflict-free

// ---------------- threefry2x32 with key (0,1) = jax.random.key(1) -------
__device__ __forceinline__ unsigned rotl32(unsigned x, unsigned r) {
    return (x << r) | (x >> (32u - r));
}

__device__ __forceinline__ void threefry2x32_01(unsigned x0, unsigned x1,
                                                unsigned& y0, unsigned& y1) {
    const unsigned ks0 = 0u, ks1 = 1u, ks2 = 0x1BD11BDBu;
    x0 += ks0; x1 += ks1;
#define TF_R(r) { x0 += x1; x1 = rotl32(x1, (r)); x1 ^= x0; }
    TF_R(13) TF_R(15) TF_R(26) TF_R(6)   x0 += ks1; x1 += ks2 + 1u;
    TF_R(17) TF_R(29) TF_R(16) TF_R(24)  x0 += ks2; x1 += ks0 + 2u;
    TF_R(13) TF_R(15) TF_R(26) TF_R(6)   x0 += ks0; x1 += ks1 + 3u;
    TF_R(17) TF_R(29) TF_R(16) TF_R(24)  x0 += ks1; x1 += ks2 + 4u;
    TF_R(13) TF_R(15) TF_R(26) TF_R(6)   x0 += ks2; x1 += ks0 + 5u;
#undef TF_R
    y0 = x0; y1 = x1;
}

__device__ __forceinline__ unsigned short f2bf(float f) {   // RNE
    unsigned u = __float_as_uint(f);
    unsigned r = (u + 0x7fffu + ((u >> 16) & 1u)) >> 16;
    return (unsigned short)r;
}
__device__ __forceinline__ float bf2f(unsigned short b) {
    return __uint_as_float(((unsigned)b) << 16);
}

// ---------------- K0: detect edge width + zero bhist --------------------
__global__ __launch_bounds__(256) void k_detect(const unsigned* __restrict__ ei,
                                                unsigned* __restrict__ flag,
                                                int* __restrict__ bhist) {
    __shared__ unsigned red[256];
    for (int i = threadIdx.x; i < NBKT; i += 256) bhist[i] = 0;
    unsigned v = 0;
    for (int i = threadIdx.x; i < 4096; i += 256) v |= ei[2 * i + 1];
    red[threadIdx.x] = v;
    __syncthreads();
    for (int s = 128; s; s >>= 1) {
        if (threadIdx.x < s) red[threadIdx.x] |= red[threadIdx.x + s];
        __syncthreads();
    }
    if (threadIdx.x == 0) *flag = (red[0] == 0u) ? 1u : 0u;  // 1 => int64
}

__device__ __forceinline__ int load_idx(const int* __restrict__ ei,
                                        int logical, unsigned wide) {
    return ei[wide ? (logical << 1) : logical];
}

// ---------------- K1: h(bf16) = x @ W, 4x4 register blocking ------------
// 128-row tile, thread = 4 rows (strided by 32) x 4 cols. Per 4 k's:
// 4 x-b128 + 4 W-b128 for 64 FMAs (8 FMA/LDS-instr). Conflict-free:
// x rows rg+32m -> addr (rg*68)%32 = 4*(rg%8), all 8 bank-quads distinct;
// W reads broadcast per cg with 8 distinct bank-quads.
__global__ __launch_bounds__(256) void k_gemm(
    const float* __restrict__ x, const float* __restrict__ W,
    const float* __restrict__ att_s, const float* __restrict__ att_d,
    unsigned short* __restrict__ h16,
    float* __restrict__ a_s, float* __restrict__ a_d)
{
    __shared__ float Ws[256 * 32];         // 32 KB
    __shared__ float xs[GROWS * XPAD];     // 34.8 KB
    const int tid = threadIdx.x;

    #pragma unroll
    for (int i = 0; i < 8; ++i) {          // stage W once
        int idx = i * 1024 + tid * 4;
        *reinterpret_cast<float4*>(Ws + idx) =
            *reinterpret_cast<const float4*>(W + idx);
    }

    const int rg = tid >> 3;               // 0..31
    const int cg = tid & 7;                // 0..7
    const int c0 = cg * 4;
    const float4 avs = *reinterpret_cast<const float4*>(att_s + c0);
    const float4 avd = *reinterpret_cast<const float4*>(att_d + c0);
    const int row0 = blockIdx.x * GROWS;

    float4 acc[4];
    #pragma unroll
    for (int m = 0; m < 4; ++m) acc[m] = make_float4(0.f, 0.f, 0.f, 0.f);

    for (int kc = 0; kc < 256; kc += 64) {
        __syncthreads();
        #pragma unroll
        for (int i = 0; i < 8; ++i) {      // stage 128x64 chunk
            int idx = i * 1024 + tid * 4;
            int r = idx >> 6, c = idx & 63;
            if (row0 + r < NN)
                *reinterpret_cast<float4*>(xs + r * XPAD + c) =
                    *reinterpret_cast<const float4*>(
                        x + (size_t)(row0 + r) * 256 + kc + c);
        }
        __syncthreads();
        #pragma unroll 4
        for (int k0 = 0; k0 < 64; k0 += 4) {
            float4 xv[4];
            #pragma unroll
            for (int m = 0; m < 4; ++m)
                xv[m] = *reinterpret_cast<const float4*>(
                    xs + (rg + 32 * m) * XPAD + k0);
            #pragma unroll
            for (int q = 0; q < 4; ++q) {
                float4 wv = *reinterpret_cast<const float4*>(
                    Ws + (kc + k0 + q) * 32 + c0);
                #pragma unroll
                for (int m = 0; m < 4; ++m) {
                    float xq = (q == 0) ? xv[m].x : (q == 1) ? xv[m].y
                             : (q == 2) ? xv[m].z : xv[m].w;
                    acc[m].x = fmaf(xq, wv.x, acc[m].x);
                    acc[m].y = fmaf(xq, wv.y, acc[m].y);
                    acc[m].z = fmaf(xq, wv.z, acc[m].z);
                    acc[m].w = fmaf(xq, wv.w, acc[m].w);
                }
            }
        }
    }
    #pragma unroll
    for (int m = 0; m < 4; ++m) {
        const int row = row0 + rg + 32 * m;
        if (row >= NN) continue;
        ushort4 hb;
        hb.x = f2bf(acc[m].x); hb.y = f2bf(acc[m].y);
        hb.z = f2bf(acc[m].z); hb.w = f2bf(acc[m].w);
        *reinterpret_cast<ushort4*>(h16 + (size_t)row * 32 + c0) = hb;
        float v1 = acc[m].x * avs.x + acc[m].y * avs.y
                 + acc[m].z * avs.z + acc[m].w * avs.w;
        float v2 = acc[m].x * avd.x + acc[m].y * avd.y
                 + acc[m].z * avd.z + acc[m].w * avd.w;
        #pragma unroll
        for (int off = 4; off; off >>= 1) {    // reduce over 8 cg lanes
            v1 += __shfl_xor(v1, off, 8);
            v2 += __shfl_xor(v2, off, 8);
        }
        if (cg == 0) { a_s[row] = v1; a_d[row] = v2; }
    }
}

// ---------------- K_A: global bucket histogram (LDS-staged) -------------
__global__ __launch_bounds__(256) void k_hist(
    const int* __restrict__ ei, const unsigned* __restrict__ flag,
    int* __restrict__ bhist)
{
    __shared__ int hl[NBKT];
    const int tid = threadIdx.x;
    for (int i = tid; i < NBKT; i += 256) hl[i] = 0;
    __syncthreads();
    const unsigned wide = *flag;
    const int base = blockIdx.x * 8192;
    #pragma unroll
    for (int k = 0; k < 32; ++k) {
        int e = base + k * 256 + tid;
        if (e < EE) {
            unsigned d = (unsigned)load_idx(ei, EE + e, wide);
            atomicAdd(&hl[d / DPB], 1);
        }
    }
    __syncthreads();
    for (int i = tid; i < NBKT; i += 256)
        if (hl[i]) atomicAdd(&bhist[i], hl[i]);
}

// ---------------- K_B: scan 512 bucket counts -> boffs, gcursor ---------
__global__ __launch_bounds__(256) void k_scan(
    const int* __restrict__ bhist, int* __restrict__ boffs,
    int* __restrict__ gcursor)
{
    __shared__ int pair[256];
    const int t = threadIdx.x;
    int a0 = bhist[2 * t], a1 = bhist[2 * t + 1];
    pair[t] = a0 + a1;
    __syncthreads();
    for (int off = 1; off < 256; off <<= 1) {
        int add = (t >= off) ? pair[t - off] : 0;
        __syncthreads();
        pair[t] += add;
        __syncthreads();
    }
    int excl = pair[t] - a0 - a1;
    boffs[2 * t] = excl;           gcursor[2 * t] = excl;
    boffs[2 * t + 1] = excl + a0;  gcursor[2 * t + 1] = excl + a0;
    if (t == 255) boffs[NBKT] = pair[255];
}

// ---------------- K_C: multisplit scatter (coalesced writes) ------------
__global__ __launch_bounds__(256) void k_msplit(
    const int* __restrict__ ei, const unsigned* __restrict__ flag,
    int* __restrict__ gcursor, int2* __restrict__ packed)
{
    __shared__ int2 staged[RND];       // 48 KB
    __shared__ int hist[NBKT], base[NBKT], rcnt[NBKT], gposL[NBKT];
    __shared__ int pair[256];
    const int tid = threadIdx.x;
    const int chunk0 = blockIdx.x * RND;
    const unsigned wide = *flag;

    for (int i = tid; i < NBKT; i += 256) { hist[i] = 0; rcnt[i] = 0; }
    __syncthreads();
    #pragma unroll
    for (int k = 0; k < RND / 256; ++k) {
        int e = chunk0 + k * 256 + tid;
        if (e < EE) {
            unsigned d = (unsigned)load_idx(ei, EE + e, wide);
            atomicAdd(&hist[d / DPB], 1);
        }
    }
    __syncthreads();
    int h0 = hist[2 * tid], h1 = hist[2 * tid + 1];
    pair[tid] = h0 + h1;
    __syncthreads();
    for (int off = 1; off < 256; off <<= 1) {
        int add = (tid >= off) ? pair[tid - off] : 0;
        __syncthreads();
        pair[tid] += add;
        __syncthreads();
    }
    int excl = pair[tid] - h0 - h1;
    base[2 * tid] = excl;
    base[2 * tid + 1] = excl + h0;
    for (int b = tid; b < NBKT; b += 256) {
        int c = hist[b];
        if (c) gposL[b] = atomicAdd(&gcursor[b], c);
    }
    __syncthreads();
    #pragma unroll
    for (int k = 0; k < RND / 256; ++k) {
        int e = chunk0 + k * 256 + tid;
        if (e < EE) {
            int s = load_idx(ei, e, wide);
            int d = load_idx(ei, EE + e, wide);
            int b = (unsigned)d / DPB;
            int lp = base[b] + atomicAdd(&rcnt[b], 1);
            staged[lp] = make_int2(s, d);
        }
    }
    __syncthreads();
    int nv = EE - chunk0; if (nv > RND) nv = RND;
    for (int i = tid; i < nv; i += 256) {
        int2 ed = staged[i];
        int b = (unsigned)ed.y / DPB;
        packed[gposL[b] + (i - base[b])] = ed;
    }
}

// ---------------- K_D: self-contained bucket sort + aggregate -----------
__global__ __launch_bounds__(1024) void k_aggr(
    const int2* __restrict__ packed, const int* __restrict__ boffs,
    const unsigned short* __restrict__ h16,
    const float* __restrict__ a_s, const float* __restrict__ a_d,
    const float* __restrict__ bias, float* __restrict__ out)
{
    __shared__ int srt[LCAP];          // 32 KB
    __shared__ int cntL[DPB];
    __shared__ int cur[DPB];
    __shared__ int sc[256];
    const int tid = threadIdx.x;
    const int b = blockIdx.x;
    const int d0 = b * DPB;
    int cnt = NN - d0; if (cnt > DPB) cnt = DPB;
    if (cnt <= 0) return;
    const int gb0 = boffs[b], gb1 = boffs[b + 1];
    const int m = gb1 - gb0;

    if (tid < DPB) cntL[tid] = 0;
    __syncthreads();
    for (int i = tid; i < m; i += 1024)                 // pass 1: degrees
        atomicAdd(&cntL[packed[gb0 + i].y - d0], 1);
    __syncthreads();
    if (tid < 256) sc[tid] = (tid < cnt) ? cntL[tid] : 0;
    __syncthreads();
    for (int off = 1; off < 256; off <<= 1) {           // Hillis-Steele
        int add = (tid < 256 && tid >= off) ? sc[tid - off] : 0;
        __syncthreads();
        if (tid < 256) sc[tid] += add;
        __syncthreads();
    }
    if (tid < cnt) cur[tid] = sc[tid] - cntL[tid];      // exclusive start
    __syncthreads();
    for (int i = tid; i < m; i += 1024) {               // pass 2: place
        int2 ed = packed[gb0 + i];
        int pos = atomicAdd(&cur[ed.y - d0], 1);
        if (pos < LCAP) srt[pos] = ed.x;
    }
    __syncthreads();
    const int hw = tid >> 5;
    const int j  = tid & 31;
    for (int nl = hw; nl < cnt; nl += 32) {
        const int d = d0 + nl;
        const float ad = a_d[d];
        const int e0 = (nl == 0) ? 0 : cur[nl - 1];
        const int e1 = cur[nl];
        float acc = 0.f, den = 0.f;
        int i = e0;
        for (; i + 1 < e1; i += 2) {                    // unroll-2 for MLP
            int s1 = srt[i], s2 = srt[i + 1];
            float al1 = a_s[s1] + ad;
            float al2 = a_s[s2] + ad;
            float hv1 = bf2f(h16[(size_t)s1 * 32 + j]);
            float hv2 = bf2f(h16[(size_t)s2 * 32 + j]);
            al1 = (al1 >= 0.f) ? al1 : 0.2f * al1;
            al2 = (al2 >= 0.f) ? al2 : 0.2f * al2;
            float w1 = __expf(al1), w2 = __expf(al2);
            acc = fmaf(w1, hv1, acc); den += w1;
            acc = fmaf(w2, hv2, acc); den += w2;
        }
        if (i < e1) {
            int s1 = srt[i];
            float al1 = a_s[s1] + ad;
            al1 = (al1 >= 0.f) ? al1 : 0.2f * al1;
            float w1 = __expf(al1);
            acc = fmaf(w1, bf2f(h16[(size_t)s1 * 32 + j]), acc); den += w1;
        }
        float al = a_s[d] + ad;                         // self-loop
        al = (al >= 0.f) ? al : 0.2f * al;
        float w = __expf(al);
        acc = fmaf(w, bf2f(h16[(size_t)d * 32 + j]), acc); den += w;
        float v = fmaxf(acc / den + bias[j], 0.f);      // fused epilogue
        int t = d * 32 + j;
        unsigned y0, y1;
        threefry2x32_01(0u, (unsigned)t, y0, y1);
        out[t] = ((y0 ^ y1) >> 31) ? 0.f : v * 2.f;
    }
}

extern "C" void kernel_launch(void* const* d_in, const int* in_sizes, int n_in,
                              void* d_out, int out_size, void* d_ws, size_t ws_size,
                              hipStream_t stream) {
    const float* x     = (const float*)d_in[0];
    const float* W     = (const float*)d_in[1];
    const float* att_s = (const float*)d_in[2];
    const float* att_d = (const float*)d_in[3];
    const float* bias  = (const float*)d_in[4];
    const int*   ei    = (const int*)d_in[5];
    float* out = (float*)d_out;

    // ws: packed[EE] int2 | h16[NN*32] bf16 | a_s[NN] | a_d[NN]
    //     | bhist[512] | boffs[513] | gcursor[512] | flag
    int2* packed = (int2*)d_ws;
    unsigned short* h16 = (unsigned short*)(packed + EE);
    float* a_s = (float*)(h16 + (size_t)NN * FO);
    float* a_d = a_s + NN;
    int* bhist = (int*)(a_d + NN);
    int* boffs = bhist + NBKT;
    int* gcursor = boffs + (NBKT + 1);
    unsigned* flag = (unsigned*)(gcursor + NBKT);

    k_detect<<<1, 256, 0, stream>>>((const unsigned*)ei, flag, bhist);
    k_gemm<<<(NN + GROWS - 1) / GROWS, 256, 0, stream>>>(
        x, W, att_s, att_d, h16, a_s, a_d);
    k_hist<<<(EE + 8191) / 8192, 256, 0, stream>>>(ei, flag, bhist);
    k_scan<<<1, 256, 0, stream>>>(bhist, boffs, gcursor);
    k_msplit<<<(EE + RND - 1) / RND, 256, 0, stream>>>(ei, flag, gcursor, packed);
    k_aggr<<<(NN + DPB - 1) / DPB, 1024, 0, stream>>>(packed, boffs, h16, a_s, a_d, bias, out);
}

// Round 9
// 120.738 us; speedup vs baseline: 3.1662x; 1.2037x over previous
//
#include <hip/hip_runtime.h>

#define NN 100000
#define EE 1600000
#define FO 32
#define NBKT 512
#define DPB 196            // dst nodes per bucket; NBKT*DPB = 100352 >= NN
#define RND 6144           // edges per multisplit block (LDS staging 48KB)
#define LCAP 8192          // per-bucket edge capacity in k_aggr LDS (32KB)
#define NTILES 6250        // NN/16 row-tiles for mfma gemm

typedef __attribute__((ext_vector_type(8))) short short8;   // 8 bf16
typedef __attribute__((ext_vector_type(4))) float f32x4;

// ---------------- threefry2x32 with key (0,1) = jax.random.key(1) -------
__device__ __forceinline__ unsigned rotl32(unsigned x, unsigned r) {
    return (x << r) | (x >> (32u - r));
}

__device__ __forceinline__ void threefry2x32_01(unsigned x0, unsigned x1,
                                                unsigned& y0, unsigned& y1) {
    const unsigned ks0 = 0u, ks1 = 1u, ks2 = 0x1BD11BDBu;
    x0 += ks0; x1 += ks1;
#define TF_R(r) { x0 += x1; x1 = rotl32(x1, (r)); x1 ^= x0; }
    TF_R(13) TF_R(15) TF_R(26) TF_R(6)   x0 += ks1; x1 += ks2 + 1u;
    TF_R(17) TF_R(29) TF_R(16) TF_R(24)  x0 += ks2; x1 += ks0 + 2u;
    TF_R(13) TF_R(15) TF_R(26) TF_R(6)   x0 += ks0; x1 += ks1 + 3u;
    TF_R(17) TF_R(29) TF_R(16) TF_R(24)  x0 += ks1; x1 += ks2 + 4u;
    TF_R(13) TF_R(15) TF_R(26) TF_R(6)   x0 += ks2; x1 += ks0 + 5u;
#undef TF_R
    y0 = x0; y1 = x1;
}

__device__ __forceinline__ unsigned short f2bf(float f) {   // RNE
    unsigned u = __float_as_uint(f);
    unsigned r = (u + 0x7fffu + ((u >> 16) & 1u)) >> 16;
    return (unsigned short)r;
}
__device__ __forceinline__ float bf2f(unsigned short b) {
    return __uint_as_float(((unsigned)b) << 16);
}

// ---------------- K0: detect edge width + zero bhist --------------------
__global__ __launch_bounds__(256) void k_detect(const unsigned* __restrict__ ei,
                                                unsigned* __restrict__ flag,
                                                int* __restrict__ bhist) {
    __shared__ unsigned red[256];
    for (int i = threadIdx.x; i < NBKT; i += 256) bhist[i] = 0;
    unsigned v = 0;
    for (int i = threadIdx.x; i < 4096; i += 256) v |= ei[2 * i + 1];
    red[threadIdx.x] = v;
    __syncthreads();
    for (int s = 128; s; s >>= 1) {
        if (threadIdx.x < s) red[threadIdx.x] |= red[threadIdx.x + s];
        __syncthreads();
    }
    if (threadIdx.x == 0) *flag = (red[0] == 0u) ? 1u : 0u;  // 1 => int64
}

__device__ __forceinline__ int load_idx(const int* __restrict__ ei,
                                        int logical, unsigned wide) {
    return ei[wide ? (logical << 1) : logical];
}

// ---------------- K1: h = x @ W via MFMA, no LDS, no syncthreads --------
// One wave per 16-row tile. A-frag: lane l holds row (l&15), k=(l>>4)*8+j
// (32B/lane from global: 16 rows x 128B contiguous -> fully coalesced).
// B-frags (W bf16): built once, 8 kt x 2 nt = 64 VGPRs.
// C/D: col=lane&15, row=(lane>>4)*4+reg  [m89-verified].
__global__ __launch_bounds__(256) void k_gemm(
    const float* __restrict__ x, const float* __restrict__ W,
    const float* __restrict__ att_s, const float* __restrict__ att_d,
    unsigned short* __restrict__ h16,
    float* __restrict__ a_s, float* __restrict__ a_d)
{
    const int lane = threadIdx.x & 63;
    const int wid  = threadIdx.x >> 6;
    const int tile = blockIdx.x * 4 + wid;
    if (tile >= NTILES) return;
    const int c = lane & 15;
    const int g = lane >> 4;

    short8 bfrag[8][2];
    #pragma unroll
    for (int kt = 0; kt < 8; ++kt)
        #pragma unroll
        for (int nt = 0; nt < 2; ++nt) {
            short8 f;
            #pragma unroll
            for (int j = 0; j < 8; ++j)
                f[j] = (short)f2bf(W[(kt * 32 + g * 8 + j) * 32 + nt * 16 + c]);
            bfrag[kt][nt] = f;
        }

    const int row0 = tile * 16;
    const float* xrow = x + (size_t)(row0 + c) * 256 + g * 8;
    f32x4 acc0 = {0.f, 0.f, 0.f, 0.f};
    f32x4 acc1 = {0.f, 0.f, 0.f, 0.f};

    #pragma unroll
    for (int kt = 0; kt < 8; ++kt) {
        float4 xa = *reinterpret_cast<const float4*>(xrow + kt * 32);
        float4 xb = *reinterpret_cast<const float4*>(xrow + kt * 32 + 4);
        short8 af;
        af[0] = (short)f2bf(xa.x); af[1] = (short)f2bf(xa.y);
        af[2] = (short)f2bf(xa.z); af[3] = (short)f2bf(xa.w);
        af[4] = (short)f2bf(xb.x); af[5] = (short)f2bf(xb.y);
        af[6] = (short)f2bf(xb.z); af[7] = (short)f2bf(xb.w);
        acc0 = __builtin_amdgcn_mfma_f32_16x16x32_bf16(af, bfrag[kt][0], acc0, 0, 0, 0);
        acc1 = __builtin_amdgcn_mfma_f32_16x16x32_bf16(af, bfrag[kt][1], acc1, 0, 0, 0);
    }

    const float s0 = att_s[c], s1 = att_s[c + 16];
    const float t0 = att_d[c], t1 = att_d[c + 16];
    #pragma unroll
    for (int q = 0; q < 4; ++q) {
        const int row = row0 + g * 4 + q;
        h16[(size_t)row * 32 + c]      = f2bf(acc0[q]);
        h16[(size_t)row * 32 + 16 + c] = f2bf(acc1[q]);
        float v1 = acc0[q] * s0 + acc1[q] * s1;
        float v2 = acc0[q] * t0 + acc1[q] * t1;
        #pragma unroll
        for (int off = 8; off; off >>= 1) {
            v1 += __shfl_xor(v1, off, 16);
            v2 += __shfl_xor(v2, off, 16);
        }
        if (c == 0) { a_s[row] = v1; a_d[row] = v2; }
    }
}

// ---------------- K_A: global bucket histogram (LDS-staged) -------------
__global__ __launch_bounds__(256) void k_hist(
    const int* __restrict__ ei, const unsigned* __restrict__ flag,
    int* __restrict__ bhist)
{
    __shared__ int hl[NBKT];
    const int tid = threadIdx.x;
    for (int i = tid; i < NBKT; i += 256) hl[i] = 0;
    __syncthreads();
    const unsigned wide = *flag;
    const int base = blockIdx.x * 8192;
    #pragma unroll
    for (int k = 0; k < 32; ++k) {
        int e = base + k * 256 + tid;
        if (e < EE) {
            unsigned d = (unsigned)load_idx(ei, EE + e, wide);
            atomicAdd(&hl[d / DPB], 1);
        }
    }
    __syncthreads();
    for (int i = tid; i < NBKT; i += 256)
        if (hl[i]) atomicAdd(&bhist[i], hl[i]);
}

// ---------------- K_B: scan 512 bucket counts -> boffs, gcursor ---------
__global__ __launch_bounds__(256) void k_scan(
    const int* __restrict__ bhist, int* __restrict__ boffs,
    int* __restrict__ gcursor)
{
    __shared__ int pair[256];
    const int t = threadIdx.x;
    int a0 = bhist[2 * t], a1 = bhist[2 * t + 1];
    pair[t] = a0 + a1;
    __syncthreads();
    for (int off = 1; off < 256; off <<= 1) {
        int add = (t >= off) ? pair[t - off] : 0;
        __syncthreads();
        pair[t] += add;
        __syncthreads();
    }
    int excl = pair[t] - a0 - a1;
    boffs[2 * t] = excl;           gcursor[2 * t] = excl;
    boffs[2 * t + 1] = excl + a0;  gcursor[2 * t + 1] = excl + a0;
    if (t == 255) boffs[NBKT] = pair[255];
}

// ---------------- K_C: multisplit scatter (coalesced writes) ------------
__global__ __launch_bounds__(256) void k_msplit(
    const int* __restrict__ ei, const unsigned* __restrict__ flag,
    int* __restrict__ gcursor, int2* __restrict__ packed)
{
    __shared__ int2 staged[RND];       // 48 KB
    __shared__ int hist[NBKT], base[NBKT], rcnt[NBKT], gposL[NBKT];
    __shared__ int pair[256];
    const int tid = threadIdx.x;
    const int chunk0 = blockIdx.x * RND;
    const unsigned wide = *flag;

    for (int i = tid; i < NBKT; i += 256) { hist[i] = 0; rcnt[i] = 0; }
    __syncthreads();
    #pragma unroll
    for (int k = 0; k < RND / 256; ++k) {
        int e = chunk0 + k * 256 + tid;
        if (e < EE) {
            unsigned d = (unsigned)load_idx(ei, EE + e, wide);
            atomicAdd(&hist[d / DPB], 1);
        }
    }
    __syncthreads();
    int h0 = hist[2 * tid], h1 = hist[2 * tid + 1];
    pair[tid] = h0 + h1;
    __syncthreads();
    for (int off = 1; off < 256; off <<= 1) {
        int add = (tid >= off) ? pair[tid - off] : 0;
        __syncthreads();
        pair[tid] += add;
        __syncthreads();
    }
    int excl = pair[tid] - h0 - h1;
    base[2 * tid] = excl;
    base[2 * tid + 1] = excl + h0;
    for (int b = tid; b < NBKT; b += 256) {
        int c = hist[b];
        if (c) gposL[b] = atomicAdd(&gcursor[b], c);
    }
    __syncthreads();
    #pragma unroll
    for (int k = 0; k < RND / 256; ++k) {
        int e = chunk0 + k * 256 + tid;
        if (e < EE) {
            int s = load_idx(ei, e, wide);
            int d = load_idx(ei, EE + e, wide);
            int b = (unsigned)d / DPB;
            int lp = base[b] + atomicAdd(&rcnt[b], 1);
            staged[lp] = make_int2(s, d);
        }
    }
    __syncthreads();
    int nv = EE - chunk0; if (nv > RND) nv = RND;
    for (int i = tid; i < nv; i += 256) {
        int2 ed = staged[i];
        int b = (unsigned)ed.y / DPB;
        packed[gposL[b] + (i - base[b])] = ed;
    }
}

// ---------------- K_D: self-contained bucket sort + aggregate -----------
__global__ __launch_bounds__(1024) void k_aggr(
    const int2* __restrict__ packed, const int* __restrict__ boffs,
    const unsigned short* __restrict__ h16,
    const float* __restrict__ a_s, const float* __restrict__ a_d,
    const float* __restrict__ bias, float* __restrict__ out)
{
    __shared__ int srt[LCAP];          // 32 KB
    __shared__ int cntL[DPB];
    __shared__ int cur[DPB];
    __shared__ int sc[256];
    const int tid = threadIdx.x;
    const int b = blockIdx.x;
    const int d0 = b * DPB;
    int cnt = NN - d0; if (cnt > DPB) cnt = DPB;
    if (cnt <= 0) return;
    const int gb0 = boffs[b], gb1 = boffs[b + 1];
    const int m = gb1 - gb0;

    if (tid < DPB) cntL[tid] = 0;
    __syncthreads();
    for (int i = tid; i < m; i += 1024)                 // pass 1: degrees
        atomicAdd(&cntL[packed[gb0 + i].y - d0], 1);
    __syncthreads();
    if (tid < 256) sc[tid] = (tid < cnt) ? cntL[tid] : 0;
    __syncthreads();
    for (int off = 1; off < 256; off <<= 1) {           // Hillis-Steele
        int add = (tid < 256 && tid >= off) ? sc[tid - off] : 0;
        __syncthreads();
        if (tid < 256) sc[tid] += add;
        __syncthreads();
    }
    if (tid < cnt) cur[tid] = sc[tid] - cntL[tid];      // exclusive start
    __syncthreads();
    for (int i = tid; i < m; i += 1024) {               // pass 2: place
        int2 ed = packed[gb0 + i];
        int pos = atomicAdd(&cur[ed.y - d0], 1);
        if (pos < LCAP) srt[pos] = ed.x;
    }
    __syncthreads();
    const int hw = tid >> 5;
    const int j  = tid & 31;
    for (int nl = hw; nl < cnt; nl += 32) {
        const int d = d0 + nl;
        const float ad = a_d[d];
        const int e0 = (nl == 0) ? 0 : cur[nl - 1];
        const int e1 = cur[nl];
        float acc = 0.f, den = 0.f;
        int i = e0;
        for (; i + 1 < e1; i += 2) {                    // unroll-2 for MLP
            int s1 = srt[i], s2 = srt[i + 1];
            float al1 = a_s[s1] + ad;
            float al2 = a_s[s2] + ad;
            float hv1 = bf2f(h16[(size_t)s1 * 32 + j]);
            float hv2 = bf2f(h16[(size_t)s2 * 32 + j]);
            al1 = (al1 >= 0.f) ? al1 : 0.2f * al1;
            al2 = (al2 >= 0.f) ? al2 : 0.2f * al2;
            float w1 = __expf(al1), w2 = __expf(al2);
            acc = fmaf(w1, hv1, acc); den += w1;
            acc = fmaf(w2, hv2, acc); den += w2;
        }
        if (i < e1) {
            int s1 = srt[i];
            float al1 = a_s[s1] + ad;
            al1 = (al1 >= 0.f) ? al1 : 0.2f * al1;
            float w1 = __expf(al1);
            acc = fmaf(w1, bf2f(h16[(size_t)s1 * 32 + j]), acc); den += w1;
        }
        float al = a_s[d] + ad;                         // self-loop
        al = (al >= 0.f) ? al : 0.2f * al;
        float w = __expf(al);
        acc = fmaf(w, bf2f(h16[(size_t)d * 32 + j]), acc); den += w;
        float v = fmaxf(acc / den + bias[j], 0.f);      // fused epilogue
        int t = d * 32 + j;
        unsigned y0, y1;
        threefry2x32_01(0u, (unsigned)t, y0, y1);
        out[t] = ((y0 ^ y1) >> 31) ? 0.f : v * 2.f;
    }
}

extern "C" void kernel_launch(void* const* d_in, const int* in_sizes, int n_in,
                              void* d_out, int out_size, void* d_ws, size_t ws_size,
                              hipStream_t stream) {
    const float* x     = (const float*)d_in[0];
    const float* W     = (const float*)d_in[1];
    const float* att_s = (const float*)d_in[2];
    const float* att_d = (const float*)d_in[3];
    const float* bias  = (const float*)d_in[4];
    const int*   ei    = (const int*)d_in[5];
    float* out = (float*)d_out;

    // ws: packed[EE] int2 | h16[NN*32] bf16 | a_s[NN] | a_d[NN]
    //     | bhist[512] | boffs[513] | gcursor[512] | flag
    int2* packed = (int2*)d_ws;
    unsigned short* h16 = (unsigned short*)(packed + EE);
    float* a_s = (float*)(h16 + (size_t)NN * FO);
    float* a_d = a_s + NN;
    int* bhist = (int*)(a_d + NN);
    int* boffs = bhist + NBKT;
    int* gcursor = boffs + (NBKT + 1);
    unsigned* flag = (unsigned*)(gcursor + NBKT);

    k_detect<<<1, 256, 0, stream>>>((const unsigned*)ei, flag, bhist);
    k_gemm<<<(NTILES + 3) / 4, 256, 0, stream>>>(
        x, W, att_s, att_d, h16, a_s, a_d);
    k_hist<<<(EE + 8191) / 8192, 256, 0, stream>>>(ei, flag, bhist);
    k_scan<<<1, 256, 0, stream>>>(bhist, boffs, gcursor);
    k_msplit<<<(EE + RND - 1) / RND, 256, 0, stream>>>(ei, flag, gcursor, packed);
    k_aggr<<<(NN + DPB - 1) / DPB, 1024, 0, stream>>>(packed, boffs, h16, a_s, a_d, bias, out);
}